// Round 19
// baseline (319.992 us; speedup 1.0000x reference)
//
#include <hip/hip_runtime.h>
#include <hip/hip_bf16.h>

// Head: B=8, T=2048, D=1024, H=64, fp32 in/out.
#define BB 8
#define TT 2048
#define DD 1024
#define HH 64
#define NROWS (BB*TT)
#define SCALE 45.25483399593904f   // sqrt(2048)
#define SPLIT 4                    // flash split-K factor
#define BCOLS 320                  // qkv B panel: 192 hi + 128 lo (Q,K only)

typedef __attribute__((ext_vector_type(8))) short short8;
typedef __attribute__((ext_vector_type(4))) float f32x4;

__device__ inline ushort bf16rne(float f) {
    unsigned u = __float_as_uint(f);
    return (ushort)((u + 0x7fffu + ((u >> 16) & 1u)) >> 16);
}
__device__ inline void bfsplit(float f, ushort& hi, ushort& lo) {
    hi = bf16rne(f);
    float fh = __uint_as_float(((unsigned)hi) << 16);
    lo = bf16rne(f - fh);
}
__device__ inline void split_pack8(const float* v, int4& h4, int4& l4) {
    ushort h[8], l[8];
    #pragma unroll
    for (int j = 0; j < 8; ++j) bfsplit(v[j], h[j], l[j]);
    h4 = make_int4((int)(h[0] | ((unsigned)h[1] << 16)), (int)(h[2] | ((unsigned)h[3] << 16)),
                   (int)(h[4] | ((unsigned)h[5] << 16)), (int)(h[6] | ((unsigned)h[7] << 16)));
    l4 = make_int4((int)(l[0] | ((unsigned)l[1] << 16)), (int)(l[2] | ((unsigned)l[3] << 16)),
                   (int)(l[4] | ((unsigned)l[5] << 16)), (int)(l[6] | ((unsigned)l[7] << 16)));
}
__device__ inline float bf2f(unsigned u16) {
    return __uint_as_float(u16 << 16);
}

// async global->LDS, 16B per lane. LDS dest = wave-uniform base + lane*16.
__device__ inline void gload_lds16(const void* g, void* l) {
    __builtin_amdgcn_global_load_lds(
        (const __attribute__((address_space(1))) unsigned int*)(uintptr_t)(g),
        (__attribute__((address_space(3))) unsigned int*)(uintptr_t)(l),
        16, 0, 0);
}

// ---------------------------------------------------------------------------
// Kernel P: W prep — r9-proven swizzle (octet^(col&7)), r15 layout:
//   Wp[c][vcol][64k]; vcol 0..191 = hi(Q,K,V); vcol 192..319 = lo(Q,K only).
// ---------------------------------------------------------------------------
__global__ __launch_bounds__(256) void wprep_kernel(
        const float* __restrict__ Wq, const float* __restrict__ Wk,
        const float* __restrict__ Wv, ushort* __restrict__ Wp) {
    __shared__ float ws[64 * 65];
    const int m = blockIdx.x >> 4;      // matrix 0..2
    const int c = blockIdx.x & 15;      // k-chunk 0..15
    const float* W = (m == 0) ? Wq : (m == 1) ? Wk : Wv;
    const int tid = threadIdx.x;

    #pragma unroll
    for (int p = 0; p < 4; ++p) {
        int i = tid + p * 256;
        int r = i >> 4, q4 = i & 15;
        float4 v = *(const float4*)(W + (size_t)(c * 64 + r) * 64 + q4 * 4);
        ws[r * 65 + q4 * 4 + 0] = v.x;
        ws[r * 65 + q4 * 4 + 1] = v.y;
        ws[r * 65 + q4 * 4 + 2] = v.z;
        ws[r * 65 + q4 * 4 + 3] = v.w;
    }
    __syncthreads();

    #pragma unroll
    for (int p = 0; p < 2; ++p) {
        int gi = tid + p * 256;
        int nn = gi >> 3, g8 = gi & 7;
        int o  = g8 ^ (nn & 7);
        float v[8];
        #pragma unroll
        for (int j = 0; j < 8; ++j) v[j] = ws[(o * 8 + j) * 65 + nn];
        int4 h4, l4; split_pack8(v, h4, l4);
        const size_t cb = (size_t)c * (BCOLS * 64);
        *(int4*)(Wp + cb + (size_t)(m * 64 + nn) * 64 + g8 * 8) = h4;
        if (m < 2)   // lo panel only for Q,K
            *(int4*)(Wp + cb + (size_t)(192 + m * 64 + nn) * 64 + g8 * 8) = l4;
    }
}

// ---------------------------------------------------------------------------
// Kernel A: QKV via MFMA 16x16x32 bf16 (r16 depth-2 counted-vmcnt, unchanged).
// ---------------------------------------------------------------------------
__global__ __launch_bounds__(512) void qkv_kernel(
        const float* __restrict__ x, const ushort* __restrict__ Wp,
        float* __restrict__ Qo, ushort* __restrict__ KhiP,
        ushort* __restrict__ KloP, ushort* __restrict__ VtP) {
    __shared__ ushort Ahi[64 * 64], Alo[64 * 64];   // 8 KiB each
    __shared__ ushort Bp[3][BCOLS * 64];            // 40 KiB per buf
    const int tid  = threadIdx.x;
    const int lane = tid & 63;
    const int w    = tid >> 6;           // wave 0..7
    const int wm   = w >> 2;             // m-half (32 rows)
    const int wn   = w & 3;              // n-quarter (48 cols)
    const int n15  = lane & 15;
    const int g    = lane >> 4;
    const int csw  = n15 & 7;
    const int row0 = blockIdx.x * 64;

    f32x4 acc[2][3];
    #pragma unroll
    for (int ms = 0; ms < 2; ++ms)
        #pragma unroll
        for (int nt = 0; nt < 3; ++nt) acc[ms][nt] = (f32x4)0.f;

    const int ar = tid >> 3, aoc = tid & 7;
    const float* xrow = x + (size_t)(row0 + ar) * 1024 + aoc * 8;
    const int adi = ar * 64 + ((aoc ^ (ar & 7)) << 3);

    const ushort* wsp = Wp + (size_t)lane * 8;

    float xA[8], xB[8];
    #pragma unroll
    for (int p = 0; p < 5; ++p) {
        int j = w * 5 + p;
        gload_lds16(wsp + j * 512, &Bp[0][j * 512]);
    }
    *(float4*)(xA)     = *(const float4*)(xrow);
    *(float4*)(xA + 4) = *(const float4*)(xrow + 4);
    #pragma unroll
    for (int p = 0; p < 5; ++p) {
        int j = w * 5 + p;
        gload_lds16(wsp + (size_t)(BCOLS * 64) + j * 512, &Bp[1][j * 512]);
    }
    *(float4*)(xB)     = *(const float4*)(xrow + 64);
    *(float4*)(xB + 4) = *(const float4*)(xrow + 68);

    for (int c = 0; c < 16; ++c) {
        const int cur = c % 3;
        const int c2 = (c + 2 < 16) ? c + 2 : 15;
        {
            const ushort* s = wsp + (size_t)c2 * (BCOLS * 64);
            ushort* d = Bp[(c + 2) % 3];
            #pragma unroll
            for (int p = 0; p < 5; ++p) {
                int j = w * 5 + p;
                gload_lds16(s + j * 512, &d[j * 512]);
            }
        }
        float xN[8];
        {
            const float* src = xrow + (size_t)c2 * 64;
            *(float4*)(xN)     = *(const float4*)(src);
            *(float4*)(xN + 4) = *(const float4*)(src + 4);
        }
        asm volatile("s_waitcnt vmcnt(14)" ::: "memory");
        __builtin_amdgcn_sched_barrier(0);
        {
            int4 h4, l4; split_pack8(xA, h4, l4);
            *(int4*)&Ahi[adi] = h4;
            *(int4*)&Alo[adi] = l4;
        }
        asm volatile("s_waitcnt lgkmcnt(0)" ::: "memory");
        __builtin_amdgcn_s_barrier();
        __builtin_amdgcn_sched_barrier(0);

        #pragma unroll
        for (int kh = 0; kh < 2; ++kh) {
            const int ko = ((4 * kh + g) ^ csw) << 3;
            short8 afh[2], afl[2];
            #pragma unroll
            for (int ms = 0; ms < 2; ++ms) {
                int ao = (wm * 32 + ms * 16 + n15) * 64 + ko;
                afh[ms] = *(const short8*)&Ahi[ao];
                afl[ms] = *(const short8*)&Alo[ao];
            }
            #pragma unroll
            for (int nt = 0; nt < 3; ++nt) {
                const int colb = wn * 48 + nt * 16;
                short8 bfh = *(const short8*)&Bp[cur][(colb + n15) * 64 + ko];
                #pragma unroll
                for (int ms = 0; ms < 2; ++ms) {
                    acc[ms][nt] = __builtin_amdgcn_mfma_f32_16x16x32_bf16(
                        afh[ms], bfh, acc[ms][nt], 0, 0, 0);
                    acc[ms][nt] = __builtin_amdgcn_mfma_f32_16x16x32_bf16(
                        afl[ms], bfh, acc[ms][nt], 0, 0, 0);
                }
                if (colb < 128) {
                    short8 bfl = *(const short8*)&Bp[cur][(192 + colb + n15) * 64 + ko];
                    #pragma unroll
                    for (int ms = 0; ms < 2; ++ms)
                        acc[ms][nt] = __builtin_amdgcn_mfma_f32_16x16x32_bf16(
                            afh[ms], bfl, acc[ms][nt], 0, 0, 0);
                }
            }
        }
        __builtin_amdgcn_s_barrier();
        #pragma unroll
        for (int j = 0; j < 8; ++j) { xA[j] = xB[j]; xB[j] = xN[j]; }
    }

    const int b  = row0 >> 11;
    const int t0 = row0 & 2047;
    #pragma unroll
    for (int nt = 0; nt < 3; ++nt) {
        const int col = wn * 48 + nt * 16 + n15;
        const int mat = col >> 6;
        const int h   = col & 63;
        #pragma unroll
        for (int ms = 0; ms < 2; ++ms) {
            const int mb = row0 + wm * 32 + ms * 16 + 4 * g;
            if (mat == 0) {
                #pragma unroll
                for (int r = 0; r < 4; ++r)
                    Qo[(size_t)(mb + r) * 64 + h] = acc[ms][nt][r];
            } else if (mat == 1) {
                #pragma unroll
                for (int r = 0; r < 4; ++r) {
                    ushort hi, lo; bfsplit(acc[ms][nt][r], hi, lo);
                    KhiP[(size_t)(mb + r) * 64 + h] = hi;
                    KloP[(size_t)(mb + r) * 64 + h] = lo;
                }
            } else {
                ushort pk[4];
                #pragma unroll
                for (int r = 0; r < 4; ++r) pk[r] = bf16rne(acc[ms][nt][r]);
                const int tloc = t0 + wm * 32 + ms * 16 + 4 * g;
                *(uint2*)&VtP[((size_t)(b * 64 + h)) * 2048 + tloc] =
                    make_uint2(pk[0] | ((unsigned)pk[1] << 16),
                               pk[2] | ((unsigned)pk[3] << 16));
            }
        }
    }
}

// ---------------------------------------------------------------------------
// Kernel B: causal flash attention (r16 structure) + r19 FUSED split-K merge:
// after writing partials, threadfence + device-scope atomicAdd on a per-(b,qt)
// counter; the last finisher merges all SPLIT partials inline (reads via
// agent-scope atomic loads -> bypass L1/L2, immune to stale lines across
// graph replays) and writes the final output. combine_kernel eliminated.
// ---------------------------------------------------------------------------
__global__ __launch_bounds__(128) void attn_kernel(
        const float* __restrict__ Q, const ushort* __restrict__ Khi,
        const ushort* __restrict__ Klo, const ushort* __restrict__ Vt,
        ushort* __restrict__ PaccH, float* __restrict__ Pm,
        float* __restrict__ Pl, int* __restrict__ counters,
        float* __restrict__ out) {
    __shared__ ushort KhiL[64 * 64];   // [key][h ^ ((key&7)<<3)]
    __shared__ ushort KloL[64 * 64];
    __shared__ ushort VtL[64 * 64];    // [h][key ^ ((h&7)<<3)]
    __shared__ int lastflag;
    const int tid  = threadIdx.x;
    const int lane = tid & 63;
    const int w    = tid >> 6;
    const int n    = lane & 15;
    const int g    = lane >> 4;
    const int b    = blockIdx.y;
    const int xx   = blockIdx.x;            // 0..255, heavy-first
    const int qt   = 63 - (xx >> 2);
    const int sp   = xx & 3;
    const int q0   = qt * 32;
    const int qmin = q0 + w * 16;
    const int qrow = qmin + n;
    const int csw  = n & 7;
    const int ntiles = (q0 >> 6) + 1;
    const int it0  = (ntiles * sp) >> 2;    // last split owns the diagonal
    const int it1  = (ntiles * (sp + 1)) >> 2;

    short8 qhi0, qhi1, qlo0, qlo1;
    {
        const float* qp = Q + ((size_t)b * TT + qrow) * HH + 8 * g;
        float v0[8], v1[8];
        *(float4*)(v0)     = *(const float4*)(qp);
        *(float4*)(v0 + 4) = *(const float4*)(qp + 4);
        *(float4*)(v1)     = *(const float4*)(qp + 32);
        *(float4*)(v1 + 4) = *(const float4*)(qp + 36);
        #pragma unroll
        for (int j = 0; j < 8; ++j) {
            ushort hi, lo;
            bfsplit(v0[j], hi, lo); qhi0[j] = (short)hi; qlo0[j] = (short)lo;
            bfsplit(v1[j], hi, lo); qhi1[j] = (short)hi; qlo1[j] = (short)lo;
        }
    }

    f32x4 accO[4];
    #pragma unroll
    for (int t = 0; t < 4; ++t) accO[t] = (f32x4)0.f;
    float m = -1e30f, l = 0.f;

    const ushort* gkh = Khi + (size_t)b * TT * HH;
    const ushort* gkl = Klo + (size_t)b * TT * HH;
    const ushort* gvt = Vt + (size_t)b * 64 * TT;

    const int crow = lane >> 3;             // row within 8-row chunk
    const int coct = lane & 7;              // LDS octet position

    for (int it = it0; it < it1; ++it) {
        const int kb = it * 64;
        __syncthreads();                    // prev compute done with LDS
        #pragma unroll
        for (int p = 0; p < 4; ++p) {
            const int cc  = w * 4 + p;      // chunk 0..7
            const int row = (cc << 3) + crow;
            const int soc = coct ^ (row & 7);
            gload_lds16(gkh + (size_t)(kb + row) * HH + (soc << 3), &KhiL[cc << 9]);
            gload_lds16(gkl + (size_t)(kb + row) * HH + (soc << 3), &KloL[cc << 9]);
            gload_lds16(gvt + (size_t)row * TT + kb + (soc << 3),   &VtL[cc << 9]);
        }
        __syncthreads();                    // drains vmcnt -> tiles ready

        f32x4 s4[4];
        #pragma unroll
        for (int s = 0; s < 4; ++s) {
            const int keyl = 16 * s + n;
            const ushort* kbase = &KhiL[keyl << 6];
            const ushort* lbase = &KloL[keyl << 6];
            short8 kh0 = *(const short8*)(kbase + ((g ^ csw) << 3));
            short8 kh1 = *(const short8*)(kbase + (((4 + g) ^ csw) << 3));
            short8 kl0 = *(const short8*)(lbase + ((g ^ csw) << 3));
            short8 kl1 = *(const short8*)(lbase + (((4 + g) ^ csw) << 3));
            f32x4 a = (f32x4)0.f;
            a = __builtin_amdgcn_mfma_f32_16x16x32_bf16(kh0, qhi0, a, 0, 0, 0);
            a = __builtin_amdgcn_mfma_f32_16x16x32_bf16(kh1, qhi1, a, 0, 0, 0);
            a = __builtin_amdgcn_mfma_f32_16x16x32_bf16(kl0, qhi0, a, 0, 0, 0);
            a = __builtin_amdgcn_mfma_f32_16x16x32_bf16(kl1, qhi1, a, 0, 0, 0);
            a = __builtin_amdgcn_mfma_f32_16x16x32_bf16(kh0, qlo0, a, 0, 0, 0);
            a = __builtin_amdgcn_mfma_f32_16x16x32_bf16(kh1, qlo1, a, 0, 0, 0);
            s4[s] = a;
        }

        float sm[16];
        if (kb + 63 > qmin) {               // diagonal tile only
            #pragma unroll
            for (int s = 0; s < 4; ++s)
                #pragma unroll
                for (int r = 0; r < 4; ++r) {
                    int keyg = kb + 16 * s + 4 * g + r;
                    sm[s * 4 + r] = (keyg <= qrow) ? s4[s][r] * SCALE : -1e30f;
                }
        } else {
            #pragma unroll
            for (int s = 0; s < 4; ++s)
                #pragma unroll
                for (int r = 0; r < 4; ++r) sm[s * 4 + r] = s4[s][r] * SCALE;
        }
        float pm = sm[0];
        #pragma unroll
        for (int i = 1; i < 16; ++i) pm = fmaxf(pm, sm[i]);
        pm = fmaxf(pm, __shfl_xor(pm, 16));
        pm = fmaxf(pm, __shfl_xor(pm, 32));
        float mn = fmaxf(m, pm);
        float es = __expf(m - mn);
        float p[16], ps = 0.f;
        #pragma unroll
        for (int i = 0; i < 16; ++i) { p[i] = __expf(sm[i] - mn); ps += p[i]; }
        ps += __shfl_xor(ps, 16);
        ps += __shfl_xor(ps, 32);
        l = l * es + ps;
        m = mn;
        #pragma unroll
        for (int t = 0; t < 4; ++t)
            #pragma unroll
            for (int r = 0; r < 4; ++r) accO[t][r] *= es;

        short8 pf0, pf1;
        #pragma unroll
        for (int j = 0; j < 4; ++j) {
            pf0[j]     = (short)bf16rne(p[0 * 4 + j]);
            pf0[j + 4] = (short)bf16rne(p[1 * 4 + j]);
            pf1[j]     = (short)bf16rne(p[2 * 4 + j]);
            pf1[j + 4] = (short)bf16rne(p[3 * 4 + j]);
        }

        #pragma unroll
        for (int t = 0; t < 4; ++t) {
            const int h = 16 * t + n;
            const ushort* vb = &VtL[h << 6];
            union { int2 d[2]; short8 v; } u0, u1;
            u0.d[0] = *(const int2*)(vb + ((4 * g) ^ (csw << 3)));
            u0.d[1] = *(const int2*)(vb + ((16 + 4 * g) ^ (csw << 3)));
            u1.d[0] = *(const int2*)(vb + ((32 + 4 * g) ^ (csw << 3)));
            u1.d[1] = *(const int2*)(vb + ((48 + 4 * g) ^ (csw << 3)));
            accO[t] = __builtin_amdgcn_mfma_f32_16x16x32_bf16(u0.v, pf0, accO[t], 0, 0, 0);
            accO[t] = __builtin_amdgcn_mfma_f32_16x16x32_bf16(u1.v, pf1, accO[t], 0, 0, 0);
        }
    }

    // ---- write partials (unnormalized, bf16-packed) ----
    const size_t brow = (size_t)b * TT + qrow;
    ushort* pa = PaccH + ((size_t)sp * NROWS + brow) * 64 + 4 * g;
    #pragma unroll
    for (int t = 0; t < 4; ++t) {
        ushort e0 = bf16rne(accO[t][0]), e1 = bf16rne(accO[t][1]);
        ushort e2 = bf16rne(accO[t][2]), e3 = bf16rne(accO[t][3]);
        *(uint2*)(pa + 16 * t) = make_uint2(e0 | ((unsigned)e1 << 16),
                                            e2 | ((unsigned)e3 << 16));
    }
    if (g == 0) {
        Pm[(size_t)sp * NROWS + brow] = m;
        Pl[(size_t)sp * NROWS + brow] = l;
    }

    // ---- fused split-K merge: last finisher for (b,qt) merges all splits ----
    __threadfence();                        // release: partials -> coherence pt
    if (tid == 0) {
        int old = __hip_atomic_fetch_add(&counters[b * 64 + qt], 1,
                                         __ATOMIC_ACQ_REL,
                                         __HIP_MEMORY_SCOPE_AGENT);
        lastflag = (old == SPLIT - 1) ? 1 : 0;
    }
    __syncthreads();
    if (!lastflag) return;
    __threadfence();                        // acquire side

    const int mr   = tid >> 2;              // 0..31
    const int quad = tid & 3;               // 16-col group
    const size_t row = (size_t)b * TT + qt * 32 + mr;

    float ms2[SPLIT], ls2[SPLIT], M2 = -1e30f;
    #pragma unroll
    for (int s = 0; s < SPLIT; ++s) {
        ms2[s] = __hip_atomic_load(&Pm[(size_t)s * NROWS + row],
                                   __ATOMIC_RELAXED, __HIP_MEMORY_SCOPE_AGENT);
        ls2[s] = __hip_atomic_load(&Pl[(size_t)s * NROWS + row],
                                   __ATOMIC_RELAXED, __HIP_MEMORY_SCOPE_AGENT);
        M2 = fmaxf(M2, ms2[s]);
    }
    float wgt[SPLIT], den = 0.f;
    #pragma unroll
    for (int s = 0; s < SPLIT; ++s) {
        wgt[s] = __expf(ms2[s] - M2);
        den += wgt[s] * ls2[s];
    }
    const float inv2 = 1.0f / den;

    float o[16];
    #pragma unroll
    for (int i = 0; i < 16; ++i) o[i] = 0.f;
    #pragma unroll
    for (int s = 0; s < SPLIT; ++s) {
        const unsigned* pa2 = (const unsigned*)
            (PaccH + ((size_t)s * NROWS + row) * 64 + quad * 16);
        #pragma unroll
        for (int i = 0; i < 8; ++i) {
            unsigned uv = __hip_atomic_load(pa2 + i, __ATOMIC_RELAXED,
                                            __HIP_MEMORY_SCOPE_AGENT);
            o[2 * i]     += wgt[s] * bf2f(uv & 0xffffu);
            o[2 * i + 1] += wgt[s] * bf2f(uv >> 16);
        }
    }
    float* op2 = out + row * 64 + quad * 16;
    #pragma unroll
    for (int i = 0; i < 4; ++i)
        *(float4*)(op2 + 4 * i) = make_float4(o[4 * i] * inv2, o[4 * i + 1] * inv2,
                                              o[4 * i + 2] * inv2, o[4 * i + 3] * inv2);
}

// ---------------------------------------------------------------------------
extern "C" void kernel_launch(void* const* d_in, const int* in_sizes, int n_in,
                              void* d_out, int out_size, void* d_ws, size_t ws_size,
                              hipStream_t stream) {
    const float* x  = (const float*)d_in[0];
    const float* Wq = (const float*)d_in[1];
    const float* Wk = (const float*)d_in[2];
    const float* Wv = (const float*)d_in[3];
    float* outp = (float*)d_out;

    float*  Qw    = (float*)d_ws;                        // 4 MB
    ushort* KhiP  = (ushort*)(Qw + (size_t)NROWS * HH);  // 2 MB
    ushort* KloP  = KhiP + (size_t)NROWS * HH;           // 2 MB
    ushort* VtP   = KloP + (size_t)NROWS * HH;           // 2 MB
    ushort* Wp    = VtP + (size_t)NROWS * HH;            // 640 KB (16*320*64*2B)
    ushort* PaccH = Wp + (size_t)16 * BCOLS * 64;        // 8 MB bf16 partials
    float*  Pm    = (float*)(PaccH + (size_t)SPLIT * NROWS * HH);  // 256 KB
    float*  Pl    = Pm + (size_t)SPLIT * NROWS;                    // 256 KB
    int*    ctr   = (int*)(Pl + (size_t)SPLIT * NROWS);            // 2 KB

    hipMemsetAsync(ctr, 0, BB * 64 * sizeof(int), stream);  // zero merge counters
    wprep_kernel<<<48, 256, 0, stream>>>(Wq, Wk, Wv, Wp);
    qkv_kernel<<<NROWS / 64, 512, 0, stream>>>(x, Wp, Qw, KhiP, KloP, VtP);
    attn_kernel<<<dim3(64 * SPLIT, BB), 128, 0, stream>>>(Qw, KhiP, KloP, VtP,
                                                          PaccH, Pm, Pl, ctr, outp);
}

// Round 20
// 68.063 us; speedup vs baseline: 4.7014x; 4.7014x over previous
//
#include <hip/hip_runtime.h>
#include <hip/hip_bf16.h>

// Head: B=8, T=2048, D=1024, H=64, fp32 in/out.
#define BB 8
#define TT 2048
#define DD 1024
#define HH 64
#define NROWS (BB*TT)
#define SCALE 45.25483399593904f   // sqrt(2048)
#define SPLIT 4                    // flash split-K factor
#define BCOLS 320                  // qkv B panel: 192 hi + 128 lo (Q,K only)

typedef __attribute__((ext_vector_type(8))) short short8;
typedef __attribute__((ext_vector_type(4))) float f32x4;

__device__ inline ushort bf16rne(float f) {
    unsigned u = __float_as_uint(f);
    return (ushort)((u + 0x7fffu + ((u >> 16) & 1u)) >> 16);
}
__device__ inline void bfsplit(float f, ushort& hi, ushort& lo) {
    hi = bf16rne(f);
    float fh = __uint_as_float(((unsigned)hi) << 16);
    lo = bf16rne(f - fh);
}
__device__ inline void split_pack8(const float* v, int4& h4, int4& l4) {
    ushort h[8], l[8];
    #pragma unroll
    for (int j = 0; j < 8; ++j) bfsplit(v[j], h[j], l[j]);
    h4 = make_int4((int)(h[0] | ((unsigned)h[1] << 16)), (int)(h[2] | ((unsigned)h[3] << 16)),
                   (int)(h[4] | ((unsigned)h[5] << 16)), (int)(h[6] | ((unsigned)h[7] << 16)));
    l4 = make_int4((int)(l[0] | ((unsigned)l[1] << 16)), (int)(l[2] | ((unsigned)l[3] << 16)),
                   (int)(l[4] | ((unsigned)l[5] << 16)), (int)(l[6] | ((unsigned)l[7] << 16)));
}
__device__ inline float bf2f(unsigned u16) {
    return __uint_as_float(u16 << 16);
}

// async global->LDS, 16B per lane. LDS dest = wave-uniform base + lane*16.
__device__ inline void gload_lds16(const void* g, void* l) {
    __builtin_amdgcn_global_load_lds(
        (const __attribute__((address_space(1))) unsigned int*)(uintptr_t)(g),
        (__attribute__((address_space(3))) unsigned int*)(uintptr_t)(l),
        16, 0, 0);
}

// ---------------------------------------------------------------------------
// Kernel P: W prep — r9-proven swizzle (octet^(col&7)), r15 layout:
//   Wp[c][vcol][64k]; vcol 0..191 = hi(Q,K,V); vcol 192..319 = lo(Q,K only).
// ---------------------------------------------------------------------------
__global__ __launch_bounds__(256) void wprep_kernel(
        const float* __restrict__ Wq, const float* __restrict__ Wk,
        const float* __restrict__ Wv, ushort* __restrict__ Wp) {
    __shared__ float ws[64 * 65];
    const int m = blockIdx.x >> 4;      // matrix 0..2
    const int c = blockIdx.x & 15;      // k-chunk 0..15
    const float* W = (m == 0) ? Wq : (m == 1) ? Wk : Wv;
    const int tid = threadIdx.x;

    #pragma unroll
    for (int p = 0; p < 4; ++p) {
        int i = tid + p * 256;
        int r = i >> 4, q4 = i & 15;
        float4 v = *(const float4*)(W + (size_t)(c * 64 + r) * 64 + q4 * 4);
        ws[r * 65 + q4 * 4 + 0] = v.x;
        ws[r * 65 + q4 * 4 + 1] = v.y;
        ws[r * 65 + q4 * 4 + 2] = v.z;
        ws[r * 65 + q4 * 4 + 3] = v.w;
    }
    __syncthreads();

    #pragma unroll
    for (int p = 0; p < 2; ++p) {
        int gi = tid + p * 256;
        int nn = gi >> 3, g8 = gi & 7;
        int o  = g8 ^ (nn & 7);
        float v[8];
        #pragma unroll
        for (int j = 0; j < 8; ++j) v[j] = ws[(o * 8 + j) * 65 + nn];
        int4 h4, l4; split_pack8(v, h4, l4);
        const size_t cb = (size_t)c * (BCOLS * 64);
        *(int4*)(Wp + cb + (size_t)(m * 64 + nn) * 64 + g8 * 8) = h4;
        if (m < 2)   // lo panel only for Q,K
            *(int4*)(Wp + cb + (size_t)(192 + m * 64 + nn) * 64 + g8 * 8) = l4;
    }
}

// ---------------------------------------------------------------------------
// Kernel A: QKV via MFMA 16x16x32 bf16 (r16 depth-2 counted-vmcnt pipeline).
// ---------------------------------------------------------------------------
__global__ __launch_bounds__(512) void qkv_kernel(
        const float* __restrict__ x, const ushort* __restrict__ Wp,
        float* __restrict__ Qo, ushort* __restrict__ KhiP,
        ushort* __restrict__ KloP, ushort* __restrict__ VtP) {
    __shared__ ushort Ahi[64 * 64], Alo[64 * 64];   // 8 KiB each
    __shared__ ushort Bp[3][BCOLS * 64];            // 40 KiB per buf
    const int tid  = threadIdx.x;
    const int lane = tid & 63;
    const int w    = tid >> 6;           // wave 0..7
    const int wm   = w >> 2;             // m-half (32 rows)
    const int wn   = w & 3;              // n-quarter (48 cols)
    const int n15  = lane & 15;
    const int g    = lane >> 4;
    const int csw  = n15 & 7;
    const int row0 = blockIdx.x * 64;

    f32x4 acc[2][3];
    #pragma unroll
    for (int ms = 0; ms < 2; ++ms)
        #pragma unroll
        for (int nt = 0; nt < 3; ++nt) acc[ms][nt] = (f32x4)0.f;

    const int ar = tid >> 3, aoc = tid & 7;
    const float* xrow = x + (size_t)(row0 + ar) * 1024 + aoc * 8;
    const int adi = ar * 64 + ((aoc ^ (ar & 7)) << 3);

    const ushort* wsp = Wp + (size_t)lane * 8;

    float xA[8], xB[8];
    #pragma unroll
    for (int p = 0; p < 5; ++p) {
        int j = w * 5 + p;
        gload_lds16(wsp + j * 512, &Bp[0][j * 512]);
    }
    *(float4*)(xA)     = *(const float4*)(xrow);
    *(float4*)(xA + 4) = *(const float4*)(xrow + 4);
    #pragma unroll
    for (int p = 0; p < 5; ++p) {
        int j = w * 5 + p;
        gload_lds16(wsp + (size_t)(BCOLS * 64) + j * 512, &Bp[1][j * 512]);
    }
    *(float4*)(xB)     = *(const float4*)(xrow + 64);
    *(float4*)(xB + 4) = *(const float4*)(xrow + 68);

    for (int c = 0; c < 16; ++c) {
        const int cur = c % 3;
        const int c2 = (c + 2 < 16) ? c + 2 : 15;
        {
            const ushort* s = wsp + (size_t)c2 * (BCOLS * 64);
            ushort* d = Bp[(c + 2) % 3];
            #pragma unroll
            for (int p = 0; p < 5; ++p) {
                int j = w * 5 + p;
                gload_lds16(s + j * 512, &d[j * 512]);
            }
        }
        float xN[8];
        {
            const float* src = xrow + (size_t)c2 * 64;
            *(float4*)(xN)     = *(const float4*)(src);
            *(float4*)(xN + 4) = *(const float4*)(src + 4);
        }
        asm volatile("s_waitcnt vmcnt(14)" ::: "memory");
        __builtin_amdgcn_sched_barrier(0);
        {
            int4 h4, l4; split_pack8(xA, h4, l4);
            *(int4*)&Ahi[adi] = h4;
            *(int4*)&Alo[adi] = l4;
        }
        asm volatile("s_waitcnt lgkmcnt(0)" ::: "memory");
        __builtin_amdgcn_s_barrier();
        __builtin_amdgcn_sched_barrier(0);

        #pragma unroll
        for (int kh = 0; kh < 2; ++kh) {
            const int ko = ((4 * kh + g) ^ csw) << 3;
            short8 afh[2], afl[2];
            #pragma unroll
            for (int ms = 0; ms < 2; ++ms) {
                int ao = (wm * 32 + ms * 16 + n15) * 64 + ko;
                afh[ms] = *(const short8*)&Ahi[ao];
                afl[ms] = *(const short8*)&Alo[ao];
            }
            #pragma unroll
            for (int nt = 0; nt < 3; ++nt) {
                const int colb = wn * 48 + nt * 16;
                short8 bfh = *(const short8*)&Bp[cur][(colb + n15) * 64 + ko];
                #pragma unroll
                for (int ms = 0; ms < 2; ++ms) {
                    acc[ms][nt] = __builtin_amdgcn_mfma_f32_16x16x32_bf16(
                        afh[ms], bfh, acc[ms][nt], 0, 0, 0);
                    acc[ms][nt] = __builtin_amdgcn_mfma_f32_16x16x32_bf16(
                        afl[ms], bfh, acc[ms][nt], 0, 0, 0);
                }
                if (colb < 128) {
                    short8 bfl = *(const short8*)&Bp[cur][(192 + colb + n15) * 64 + ko];
                    #pragma unroll
                    for (int ms = 0; ms < 2; ++ms)
                        acc[ms][nt] = __builtin_amdgcn_mfma_f32_16x16x32_bf16(
                            afh[ms], bfl, acc[ms][nt], 0, 0, 0);
                }
            }
        }
        __builtin_amdgcn_s_barrier();
        #pragma unroll
        for (int j = 0; j < 8; ++j) { xA[j] = xB[j]; xB[j] = xN[j]; }
    }

    const int b  = row0 >> 11;
    const int t0 = row0 & 2047;
    #pragma unroll
    for (int nt = 0; nt < 3; ++nt) {
        const int col = wn * 48 + nt * 16 + n15;
        const int mat = col >> 6;
        const int h   = col & 63;
        #pragma unroll
        for (int ms = 0; ms < 2; ++ms) {
            const int mb = row0 + wm * 32 + ms * 16 + 4 * g;
            if (mat == 0) {
                #pragma unroll
                for (int r = 0; r < 4; ++r)
                    Qo[(size_t)(mb + r) * 64 + h] = acc[ms][nt][r];
            } else if (mat == 1) {
                #pragma unroll
                for (int r = 0; r < 4; ++r) {
                    ushort hi, lo; bfsplit(acc[ms][nt][r], hi, lo);
                    KhiP[(size_t)(mb + r) * 64 + h] = hi;
                    KloP[(size_t)(mb + r) * 64 + h] = lo;
                }
            } else {
                ushort pk[4];
                #pragma unroll
                for (int r = 0; r < 4; ++r) pk[r] = bf16rne(acc[ms][nt][r]);
                const int tloc = t0 + wm * 32 + ms * 16 + 4 * g;
                *(uint2*)&VtP[((size_t)(b * 64 + h)) * 2048 + tloc] =
                    make_uint2(pk[0] | ((unsigned)pk[1] << 16),
                               pk[2] | ((unsigned)pk[3] << 16));
            }
        }
    }
}

// ---------------------------------------------------------------------------
// Kernel B: causal flash attention (r16/r18 best-measured config):
// single-buffered LDS (24KB, 6 blocks/CU), __syncthreads-drain staging,
// split-K x4, bf16 partials, separate combine kernel.
// ---------------------------------------------------------------------------
__global__ __launch_bounds__(128) void attn_kernel(
        const float* __restrict__ Q, const ushort* __restrict__ Khi,
        const ushort* __restrict__ Klo, const ushort* __restrict__ Vt,
        ushort* __restrict__ PaccH, float* __restrict__ Pm,
        float* __restrict__ Pl) {
    __shared__ ushort KhiL[64 * 64];   // [key][h ^ ((key&7)<<3)]
    __shared__ ushort KloL[64 * 64];
    __shared__ ushort VtL[64 * 64];    // [h][key ^ ((h&7)<<3)]
    const int tid  = threadIdx.x;
    const int lane = tid & 63;
    const int w    = tid >> 6;
    const int n    = lane & 15;
    const int g    = lane >> 4;
    const int b    = blockIdx.y;
    const int xx   = blockIdx.x;            // 0..255, heavy-first
    const int qt   = 63 - (xx >> 2);
    const int sp   = xx & 3;
    const int q0   = qt * 32;
    const int qmin = q0 + w * 16;
    const int qrow = qmin + n;
    const int csw  = n & 7;
    const int ntiles = (q0 >> 6) + 1;
    const int it0  = (ntiles * sp) >> 2;    // last split owns the diagonal
    const int it1  = (ntiles * (sp + 1)) >> 2;

    short8 qhi0, qhi1, qlo0, qlo1;
    {
        const float* qp = Q + ((size_t)b * TT + qrow) * HH + 8 * g;
        float v0[8], v1[8];
        *(float4*)(v0)     = *(const float4*)(qp);
        *(float4*)(v0 + 4) = *(const float4*)(qp + 4);
        *(float4*)(v1)     = *(const float4*)(qp + 32);
        *(float4*)(v1 + 4) = *(const float4*)(qp + 36);
        #pragma unroll
        for (int j = 0; j < 8; ++j) {
            ushort hi, lo;
            bfsplit(v0[j], hi, lo); qhi0[j] = (short)hi; qlo0[j] = (short)lo;
            bfsplit(v1[j], hi, lo); qhi1[j] = (short)hi; qlo1[j] = (short)lo;
        }
    }

    f32x4 accO[4];
    #pragma unroll
    for (int t = 0; t < 4; ++t) accO[t] = (f32x4)0.f;
    float m = -1e30f, l = 0.f;

    const ushort* gkh = Khi + (size_t)b * TT * HH;
    const ushort* gkl = Klo + (size_t)b * TT * HH;
    const ushort* gvt = Vt + (size_t)b * 64 * TT;

    const int crow = lane >> 3;             // row within 8-row chunk
    const int coct = lane & 7;              // LDS octet position

    for (int it = it0; it < it1; ++it) {
        const int kb = it * 64;
        __syncthreads();                    // prev compute done with LDS
        #pragma unroll
        for (int p = 0; p < 4; ++p) {
            const int cc  = w * 4 + p;      // chunk 0..7
            const int row = (cc << 3) + crow;
            const int soc = coct ^ (row & 7);
            gload_lds16(gkh + (size_t)(kb + row) * HH + (soc << 3), &KhiL[cc << 9]);
            gload_lds16(gkl + (size_t)(kb + row) * HH + (soc << 3), &KloL[cc << 9]);
            gload_lds16(gvt + (size_t)row * TT + kb + (soc << 3),   &VtL[cc << 9]);
        }
        __syncthreads();                    // drains vmcnt -> tiles ready

        f32x4 s4[4];
        #pragma unroll
        for (int s = 0; s < 4; ++s) {
            const int keyl = 16 * s + n;
            const ushort* kbase = &KhiL[keyl << 6];
            const ushort* lbase = &KloL[keyl << 6];
            short8 kh0 = *(const short8*)(kbase + ((g ^ csw) << 3));
            short8 kh1 = *(const short8*)(kbase + (((4 + g) ^ csw) << 3));
            short8 kl0 = *(const short8*)(lbase + ((g ^ csw) << 3));
            short8 kl1 = *(const short8*)(lbase + (((4 + g) ^ csw) << 3));
            f32x4 a = (f32x4)0.f;
            a = __builtin_amdgcn_mfma_f32_16x16x32_bf16(kh0, qhi0, a, 0, 0, 0);
            a = __builtin_amdgcn_mfma_f32_16x16x32_bf16(kh1, qhi1, a, 0, 0, 0);
            a = __builtin_amdgcn_mfma_f32_16x16x32_bf16(kl0, qhi0, a, 0, 0, 0);
            a = __builtin_amdgcn_mfma_f32_16x16x32_bf16(kl1, qhi1, a, 0, 0, 0);
            a = __builtin_amdgcn_mfma_f32_16x16x32_bf16(kh0, qlo0, a, 0, 0, 0);
            a = __builtin_amdgcn_mfma_f32_16x16x32_bf16(kh1, qlo1, a, 0, 0, 0);
            s4[s] = a;
        }

        float sm[16];
        if (kb + 63 > qmin) {               // diagonal tile only
            #pragma unroll
            for (int s = 0; s < 4; ++s)
                #pragma unroll
                for (int r = 0; r < 4; ++r) {
                    int keyg = kb + 16 * s + 4 * g + r;
                    sm[s * 4 + r] = (keyg <= qrow) ? s4[s][r] * SCALE : -1e30f;
                }
        } else {
            #pragma unroll
            for (int s = 0; s < 4; ++s)
                #pragma unroll
                for (int r = 0; r < 4; ++r) sm[s * 4 + r] = s4[s][r] * SCALE;
        }
        float pm = sm[0];
        #pragma unroll
        for (int i = 1; i < 16; ++i) pm = fmaxf(pm, sm[i]);
        pm = fmaxf(pm, __shfl_xor(pm, 16));
        pm = fmaxf(pm, __shfl_xor(pm, 32));
        float mn = fmaxf(m, pm);
        float es = __expf(m - mn);
        float p[16], ps = 0.f;
        #pragma unroll
        for (int i = 0; i < 16; ++i) { p[i] = __expf(sm[i] - mn); ps += p[i]; }
        ps += __shfl_xor(ps, 16);
        ps += __shfl_xor(ps, 32);
        l = l * es + ps;
        m = mn;
        #pragma unroll
        for (int t = 0; t < 4; ++t)
            #pragma unroll
            for (int r = 0; r < 4; ++r) accO[t][r] *= es;

        short8 pf0, pf1;
        #pragma unroll
        for (int j = 0; j < 4; ++j) {
            pf0[j]     = (short)bf16rne(p[0 * 4 + j]);
            pf0[j + 4] = (short)bf16rne(p[1 * 4 + j]);
            pf1[j]     = (short)bf16rne(p[2 * 4 + j]);
            pf1[j + 4] = (short)bf16rne(p[3 * 4 + j]);
        }

        #pragma unroll
        for (int t = 0; t < 4; ++t) {
            const int h = 16 * t + n;
            const ushort* vb = &VtL[h << 6];
            union { int2 d[2]; short8 v; } u0, u1;
            u0.d[0] = *(const int2*)(vb + ((4 * g) ^ (csw << 3)));
            u0.d[1] = *(const int2*)(vb + ((16 + 4 * g) ^ (csw << 3)));
            u1.d[0] = *(const int2*)(vb + ((32 + 4 * g) ^ (csw << 3)));
            u1.d[1] = *(const int2*)(vb + ((48 + 4 * g) ^ (csw << 3)));
            accO[t] = __builtin_amdgcn_mfma_f32_16x16x32_bf16(u0.v, pf0, accO[t], 0, 0, 0);
            accO[t] = __builtin_amdgcn_mfma_f32_16x16x32_bf16(u1.v, pf1, accO[t], 0, 0, 0);
        }
    }

    // ---- write partials (unnormalized, bf16-packed) ----
    const size_t brow = (size_t)b * TT + qrow;
    ushort* pa = PaccH + ((size_t)sp * NROWS + brow) * 64 + 4 * g;
    #pragma unroll
    for (int t = 0; t < 4; ++t) {
        ushort e0 = bf16rne(accO[t][0]), e1 = bf16rne(accO[t][1]);
        ushort e2 = bf16rne(accO[t][2]), e3 = bf16rne(accO[t][3]);
        *(uint2*)(pa + 16 * t) = make_uint2(e0 | ((unsigned)e1 << 16),
                                            e2 | ((unsigned)e3 << 16));
    }
    if (g == 0) {
        Pm[(size_t)sp * NROWS + brow] = m;
        Pl[(size_t)sp * NROWS + brow] = l;
    }
}

// ---------------------------------------------------------------------------
// Kernel C: merge SPLIT bf16 partials (separate launch = cheap device fence).
// ---------------------------------------------------------------------------
__global__ __launch_bounds__(256) void combine_kernel(
        const ushort* __restrict__ PaccH, const float* __restrict__ Pm,
        const float* __restrict__ Pl, float* __restrict__ out) {
    const int u    = blockIdx.x * 256 + threadIdx.x;   // 0..65535
    const int row  = u >> 2;
    const int quad = u & 3;

    float ms[SPLIT], ls[SPLIT], M = -1e30f;
    #pragma unroll
    for (int s = 0; s < SPLIT; ++s) {
        ms[s] = Pm[(size_t)s * NROWS + row];
        ls[s] = Pl[(size_t)s * NROWS + row];
        M = fmaxf(M, ms[s]);
    }
    float wgt[SPLIT], den = 0.f;
    #pragma unroll
    for (int s = 0; s < SPLIT; ++s) {
        wgt[s] = __expf(ms[s] - M);
        den += wgt[s] * ls[s];
    }
    const float inv = 1.0f / den;

    float4 o[4];
    #pragma unroll
    for (int i = 0; i < 4; ++i) o[i] = make_float4(0.f, 0.f, 0.f, 0.f);
    #pragma unroll
    for (int s = 0; s < SPLIT; ++s) {
        const ushort* a = PaccH + ((size_t)s * NROWS + row) * 64 + quad * 16;
        #pragma unroll
        for (int i = 0; i < 4; ++i) {
            uint2 uv = *(const uint2*)(a + i * 4);
            o[i].x += wgt[s] * bf2f(uv.x & 0xffffu);
            o[i].y += wgt[s] * bf2f(uv.x >> 16);
            o[i].z += wgt[s] * bf2f(uv.y & 0xffffu);
            o[i].w += wgt[s] * bf2f(uv.y >> 16);
        }
    }
    float4* op = (float4*)(out + (size_t)row * 64 + quad * 16);
    #pragma unroll
    for (int i = 0; i < 4; ++i)
        op[i] = make_float4(o[i].x * inv, o[i].y * inv, o[i].z * inv, o[i].w * inv);
}

// ---------------------------------------------------------------------------
extern "C" void kernel_launch(void* const* d_in, const int* in_sizes, int n_in,
                              void* d_out, int out_size, void* d_ws, size_t ws_size,
                              hipStream_t stream) {
    const float* x  = (const float*)d_in[0];
    const float* Wq = (const float*)d_in[1];
    const float* Wk = (const float*)d_in[2];
    const float* Wv = (const float*)d_in[3];
    float* outp = (float*)d_out;

    float*  Qw    = (float*)d_ws;                        // 4 MB
    ushort* KhiP  = (ushort*)(Qw + (size_t)NROWS * HH);  // 2 MB
    ushort* KloP  = KhiP + (size_t)NROWS * HH;           // 2 MB
    ushort* VtP   = KloP + (size_t)NROWS * HH;           // 2 MB
    ushort* Wp    = VtP + (size_t)NROWS * HH;            // 640 KB (16*320*64*2B)
    ushort* PaccH = Wp + (size_t)16 * BCOLS * 64;        // 8 MB bf16 partials
    float*  Pm    = (float*)(PaccH + (size_t)SPLIT * NROWS * HH);  // 256 KB
    float*  Pl    = Pm + (size_t)SPLIT * NROWS;                    // 256 KB

    wprep_kernel<<<48, 256, 0, stream>>>(Wq, Wk, Wv, Wp);
    qkv_kernel<<<NROWS / 64, 512, 0, stream>>>(x, Wp, Qw, KhiP, KloP, VtP);
    attn_kernel<<<dim3(64 * SPLIT, BB), 128, 0, stream>>>(Qw, KhiP, KloP, VtP,
                                                          PaccH, Pm, Pl);
    combine_kernel<<<NROWS * 4 / 256, 256, 0, stream>>>(PaccH, Pm, Pl, outp);
}